// Round 6
// baseline (126.002 us; speedup 1.0000x reference)
//
#include <hip/hip_runtime.h>

// Fully fused mag -> ISTFT -> STFT -> phase -> ISTFT.
// N_FFT=16, HOP=4, PAD=8. B=32, K=9 bins, T=65536 frames, LW=262140.
// Interior blocks: wave-shuffle pipeline, 4 frames per lane (v4f packed math,
// dwordx4 mag loads, ds_bpermute halo exchange, zero barriers).
// 2 edge blocks per batch: validated LDS pipeline for first/last 1024 samples.

#define KB    9
#define TFR   65536
#define LW    262140

#define C1f 0.9238795325112867f
#define C2f 0.7071067811865476f
#define C3f 0.3826834323650898f

#define W1 0.03806023374435663f
#define W2 0.14644660940672627f
#define W3 0.30865828381745514f
#define W4 0.5f
#define W5 0.6913417161825449f
#define W6 0.8535533905932737f
#define W7 0.9619397662556434f

// window consts with 1/24 OLA env folded in (interior only)
#define V1 (W1*(1.f/24.f))
#define V2 (W2*(1.f/24.f))
#define V3 (W3*(1.f/24.f))
#define V4 (W4*(1.f/24.f))
#define V5 (W5*(1.f/24.f))
#define V6 (W6*(1.f/24.f))
#define V7 (W7*(1.f/24.f))
#define V8 (1.f/24.f)

// interior coverage: out frames [256, 65280); 232 frames per wave (58 lanes x 4)
#define TMIN   256
#define TMAX   65280
#define FPW    232
#define NWAVES 281            // ceil(65024/232)
#define BXI    71             // ceil(281/4) interior blocks per batch

// edge tiles
#define TILE  1024
#define NW    1048
#define NCA   265
#define NFB   259
#define MSTR  268
#define FSTR  20

typedef float v4f __attribute__((ext_vector_type(4)));

static __device__ __forceinline__ v4f mk4(float a, float b, float c, float d){
  v4f r; r.x=a; r.y=b; r.z=c; r.w=d; return r; }
static __device__ __forceinline__ v4f sp4(float c){ v4f r; r.x=c; r.y=c; r.z=c; r.w=c; return r; }
static __device__ __forceinline__ v4f vfma4(v4f a, v4f b, v4f c){ return __builtin_elementwise_fma(a,b,c); }
static __device__ __forceinline__ v4f vfma4(float a, v4f b, v4f c){ return __builtin_elementwise_fma(sp4(a),b,c); }

static __device__ __forceinline__ void phase1(float m, float Sr, float Si,
                                              float& pr, float& pi){
  float r2 = fmaf(Sr,Sr, Si*Si);
  if (r2 > 0.f) {
    float rin = __builtin_amdgcn_rsqf(r2);
    float mr = m * rin;
    pr = mr * Sr; pi = mr * Si;
  } else { pr = m; pi = 0.f; }
}
static __device__ __forceinline__ void phase4(v4f m, v4f Sr, v4f Si, v4f& pr, v4f& pi){
  float ax,bx_,cx,dx, ay,by,cy,dy;
  phase1(m.x, Sr.x, Si.x, ax, ay);
  phase1(m.y, Sr.y, Si.y, bx_, by);
  phase1(m.z, Sr.z, Si.z, cx, cy);
  phase1(m.w, Sr.w, Si.w, dx, dy);
  pr = mk4(ax,bx_,cx,dx); pi = mk4(ay,by,cy,dy);
}

__device__ __constant__ float W2C[16] = {
  0.f, W1*W1, W2*W2, W3*W3, 0.25f, W5*W5, W6*W6, W7*W7,
  1.f, W7*W7, W6*W6, W5*W5, 0.25f, W3*W3, W2*W2, W1*W1 };

#define SH(x, di) __shfl((x), lane + (di), 64)

__global__ __launch_bounds__(256) void istft_all(
    const float* __restrict__ mag, float* __restrict__ out)
{
  // edge-path LDS (unused by interior blocks)
  __shared__ __align__(16) float s_mag[KB * MSTR];
  __shared__ __align__(16) float s_fab[NCA * FSTR];
  __shared__ __align__(16) float s_wav[NW];

  const int tid = threadIdx.x;
  const int bx  = blockIdx.x;
  const int b   = blockIdx.y;
  const float* magb = mag + (size_t)b * (size_t)(KB * TFR);
  float* outb = out + (size_t)b * LW;

  if (bx < BXI) {
    // ------------- interior: 1 lane = 4 frames, shuffle halo -------------
    const int lane = tid & 63;
    const int wv   = bx * 4 + (tid >> 6);
    if (wv >= NWAVES) return;
    const int T0 = TMIN + wv * FPW;
    const int ta = T0 - 12 + 4 * lane;      // lane's frames [ta, ta+4)

    // mag columns (ta..ta+3) x 9 bins: dwordx4 loads, coalesced
    v4f R0 = *(const v4f*)(magb + 0*TFR + ta);
    v4f R1 = *(const v4f*)(magb + 1*TFR + ta);
    v4f R2 = *(const v4f*)(magb + 2*TFR + ta);
    v4f R3 = *(const v4f*)(magb + 3*TFR + ta);
    v4f R4 = *(const v4f*)(magb + 4*TFR + ta);
    v4f R5 = *(const v4f*)(magb + 5*TFR + ta);
    v4f R6 = *(const v4f*)(magb + 6*TFR + ta);
    v4f R7 = *(const v4f*)(magb + 7*TFR + ta);
    v4f R8 = *(const v4f*)(magb + 8*TFR + ta);

    // ---- stage A: irfft16 of real spectrum, windowed (w/24 folded) ----
    v4f f1,f2,f3,f4,f5,f6,f7,f8;
    {
      v4f p1=R1+R7, m1=R1-R7, p2=R2+R6, m2=R2-R6, p3=R3+R5, m3=R3-R5;
      v4f tp=R0+R8, tm=R0-R8, d13=p1-p3;
      v4f E1 = vfma4(2.f, vfma4(C1f,m1, vfma4(C2f,m2, sp4(C3f)*m3)), tm);
      v4f E2 = vfma4(2.f, vfma4(C2f,d13, -R4), tp);
      v4f E3 = vfma4(2.f, vfma4(C3f,m1, vfma4(-C2f,m2, sp4(-C1f)*m3)), tm);
      v4f E4 = vfma4(2.f, R4-p2, tp);
      v4f E5 = vfma4(2.f, vfma4(-C3f,m1, vfma4(-C2f,m2, sp4(C1f)*m3)), tm);
      v4f E6 = vfma4(-2.f, vfma4(C2f,d13, R4), tp);
      v4f E7 = vfma4(2.f, vfma4(-C1f,m1, vfma4(C2f,m2, sp4(-C3f)*m3)), tm);
      v4f E8 = vfma4(2.f, ((p2+R4)-(p1+p3)), tp);
      f1=sp4(V1)*E1; f2=sp4(V2)*E2; f3=sp4(V3)*E3; f4=sp4(V4)*E4;
      f5=sp4(V5)*E5; f6=sp4(V6)*E6; f7=sp4(V7)*E7; f8=sp4(V8)*E8;
    }

    // ---- stage A2: OLA -> wav chunks wc_r[j] = wav[4(ta+j)+r] ----
    v4f wc0, wc1, wc2, wc3;
    {
      float n4 = SH(f4.x,+1), n5 = SH(f5.x,+1), n6 = SH(f6.x,+1), n7 = SH(f7.x,+1);
      float n1x = SH(f1.x,+1), n1y = SH(f1.y,+1);
      float n2x = SH(f2.x,+1), n2y = SH(f2.y,+1);
      float n3x = SH(f3.x,+1), n3y = SH(f3.y,+1);
      float p1w = SH(f1.w,-1), p2w = SH(f2.w,-1), p3w = SH(f3.w,-1), p4w = SH(f4.w,-1);
      v4f f4p1 = mk4(f4.y, f4.z, f4.w, n4);
      v4f f5p1 = mk4(f5.y, f5.z, f5.w, n5);
      v4f f6p1 = mk4(f6.y, f6.z, f6.w, n6);
      v4f f7p1 = mk4(f7.y, f7.z, f7.w, n7);
      v4f f1p2 = mk4(f1.z, f1.w, n1x, n1y);
      v4f f2p2 = mk4(f2.z, f2.w, n2x, n2y);
      v4f f3p2 = mk4(f3.z, f3.w, n3x, n3y);
      v4f f1m1 = mk4(p1w, f1.x, f1.y, f1.z);
      v4f f2m1 = mk4(p2w, f2.x, f2.y, f2.z);
      v4f f3m1 = mk4(p3w, f3.x, f3.y, f3.z);
      v4f f4m1 = mk4(p4w, f4.x, f4.y, f4.z);
      wc0 = f4p1 + f8 + f4m1;
      wc1 = f1p2 + f5p1 + f7 + f3m1;
      wc2 = f2p2 + f6p1 + f6 + f2m1;
      wc3 = f3p2 + f7p1 + f5 + f1m1;
    }

    // ---- stage B gather: xs[4a+r] = shift(a-2)(wc_r) ----
    v4f x1,x2,x3,x4,x5,x6,x7,x8w,x9,x10,x11,x12,x13,x14,x15;
    {
      float q1z = SH(wc1.z,-1), q1w = SH(wc1.w,-1);
      float q2z = SH(wc2.z,-1), q2w = SH(wc2.w,-1);
      float q3z = SH(wc3.z,-1), q3w = SH(wc3.w,-1);
      float q0w = SH(wc0.w,-1);
      float n0x = SH(wc0.x,+1), n1x = SH(wc1.x,+1), n2x = SH(wc2.x,+1), n3x = SH(wc3.x,+1);
      x1  = mk4(q1z, q1w, wc1.x, wc1.y);
      x2  = mk4(q2z, q2w, wc2.x, wc2.y);
      x3  = mk4(q3z, q3w, wc3.x, wc3.y);
      x4  = mk4(q0w, wc0.x, wc0.y, wc0.z);
      x5  = mk4(q1w, wc1.x, wc1.y, wc1.z);
      x6  = mk4(q2w, wc2.x, wc2.y, wc2.z);
      x7  = mk4(q3w, wc3.x, wc3.y, wc3.z);
      x8w = wc0; x9 = wc1; x10 = wc2; x11 = wc3;
      x12 = mk4(wc0.y, wc0.z, wc0.w, n0x);
      x13 = mk4(wc1.y, wc1.z, wc1.w, n1x);
      x14 = mk4(wc2.y, wc2.z, wc2.w, n2x);
      x15 = mk4(wc3.y, wc3.z, wc3.w, n3x);
    }
    // window (w0=0 kills tap 0; w8=1)
    x1=sp4(W1)*x1; x2=sp4(W2)*x2; x3=sp4(W3)*x3; x4=sp4(W4)*x4; x5=sp4(W5)*x5;
    x6=sp4(W6)*x6; x7=sp4(W7)*x7; x9=sp4(W7)*x9; x10=sp4(W6)*x10; x11=sp4(W5)*x11;
    x12=sp4(W4)*x12; x13=sp4(W3)*x13; x14=sp4(W2)*x14; x15=sp4(W1)*x15;

    v4f fc1,fc2,fc3,fc4,fc5,fc6,fc7,fc8,fc9,fc10,fc11,fc12,fc13,fc14,fc15;
    {
      v4f u1=x1+x15, vv1=x1-x15, u2=x2+x14, vv2=x2-x14, u3=x3+x13, vv3=x3-x13,
          u4=x4+x12, vv4=x4-x12, u5=x5+x11, vv5=x5-x11, u6=x6+x10, vv6=x6-x10,
          u7=x7+x9,  vv7=x7-x9;
      v4f P1=u1+u7, M1=u1-u7, P2=u2+u6, M2=u2-u6, P3=u3+u5, M3=u3-u5;
      v4f D13 = P1-P3;
      v4f Sr0 = x8w + ((P1+P2)+(P3+u4));
      v4f Sr1 = vfma4(C1f,M1, vfma4(C2f,M2, sp4(C3f)*M3)) - x8w;
      v4f Sr2 = vfma4(C2f,D13, x8w - u4);
      v4f Sr3 = vfma4(C3f,M1, vfma4(-C2f,M2, sp4(-C1f)*M3)) - x8w;
      v4f Sr4 = (u4 - P2) + x8w;
      v4f Sr5 = vfma4(-C3f,M1, vfma4(-C2f,M2, sp4(C1f)*M3)) - x8w;
      v4f Sr6 = vfma4(-C2f,D13, x8w - u4);
      v4f Sr7 = vfma4(-C1f,M1, vfma4(C2f,M2, sp4(-C3f)*M3)) - x8w;
      v4f Sr8 = x8w + ((P2+u4)-(P1+P3));
      v4f Q1=vv1+vv7, N1=vv1-vv7, Q2=vv2+vv6, N2=vv2-vv6, Q3=vv3+vv5, N3=vv3-vv5;
      v4f NN = N1+N3;
      v4f Si1 = -(vfma4(C3f,Q1, vfma4(C2f,Q2, sp4(C1f)*Q3)) + vv4);
      v4f Si2 = -vfma4(C2f,NN, N2);
      v4f Si3 = -(vfma4(C1f,Q1, vfma4(C2f,Q2, sp4(-C3f)*Q3)) - vv4);
      v4f Si4 = N3 - N1;
      v4f Si5 = -(vfma4(C1f,Q1, vfma4(-C2f,Q2, sp4(-C3f)*Q3)) + vv4);
      v4f Si6 = vfma4(-C2f,NN, N2);
      v4f Si7 = -(vfma4(C3f,Q1, vfma4(-C2f,Q2, sp4(C1f)*Q3)) - vv4);

      // phase recombine
      v4f pr0,pr1,pr2,pr3,pr4,pr5,pr6,pr7,pr8;
      v4f pi1,pi2,pi3,pi4,pi5,pi6,pi7;
      pr0 = mk4((Sr0.x >= 0.f) ? R0.x : -R0.x,
                (Sr0.y >= 0.f) ? R0.y : -R0.y,
                (Sr0.z >= 0.f) ? R0.z : -R0.z,
                (Sr0.w >= 0.f) ? R0.w : -R0.w);
      phase4(R1, Sr1, Si1, pr1, pi1);
      phase4(R2, Sr2, Si2, pr2, pi2);
      phase4(R3, Sr3, Si3, pr3, pi3);
      phase4(R4, Sr4, Si4, pr4, pi4);
      phase4(R5, Sr5, Si5, pr5, pi5);
      phase4(R6, Sr6, Si6, pr6, pi6);
      phase4(R7, Sr7, Si7, pr7, pi7);
      pr8 = mk4((Sr8.x >= 0.f) ? R8.x : -R8.x,
                (Sr8.y >= 0.f) ? R8.y : -R8.y,
                (Sr8.z >= 0.f) ? R8.z : -R8.z,
                (Sr8.w >= 0.f) ? R8.w : -R8.w);

      // irfft16 of (pr + i*pi), windowed (w/24 folded)
      v4f ap1=pr1+pr7, bm1=pr1-pr7, ap2=pr2+pr6, bm2=pr2-pr6, ap3=pr3+pr5, bm3=pr3-pr5;
      v4f tp=pr0+pr8, tm=pr0-pr8, ed=ap1-ap3;
      v4f E1 = vfma4(2.f, vfma4(C1f,bm1, vfma4(C2f,bm2, sp4(C3f)*bm3)), tm);
      v4f E2 = vfma4(2.f, vfma4(C2f,ed, -pr4), tp);
      v4f E3 = vfma4(2.f, vfma4(C3f,bm1, vfma4(-C2f,bm2, sp4(-C1f)*bm3)), tm);
      v4f E4 = vfma4(2.f, pr4-ap2, tp);
      v4f E5 = vfma4(2.f, vfma4(-C3f,bm1, vfma4(-C2f,bm2, sp4(C1f)*bm3)), tm);
      v4f E6 = vfma4(-2.f, vfma4(C2f,ed, pr4), tp);
      v4f E7 = vfma4(2.f, vfma4(-C1f,bm1, vfma4(C2f,bm2, sp4(-C3f)*bm3)), tm);
      v4f E8 = vfma4(2.f, ((ap2+pr4)-(ap1+ap3)), tp);
      v4f q1=pi1+pi7, n1=pi1-pi7, q2=pi2+pi6, n2=pi2-pi6, q3=pi3+pi5, n3=pi3-pi5;
      v4f nn = n1+n3;
      v4f O1 = sp4(-2.f)*(vfma4(C3f,q1, vfma4(C2f,q2, sp4(C1f)*q3)) + pi4);
      v4f O2 = sp4(-2.f)*vfma4(C2f,nn, n2);
      v4f O3 = sp4(-2.f)*(vfma4(C1f,q1, vfma4(C2f,q2, sp4(-C3f)*q3)) - pi4);
      v4f O4 = sp4(-2.f)*(n1-n3);
      v4f O5 = sp4(-2.f)*(vfma4(C1f,q1, vfma4(-C2f,q2, sp4(-C3f)*q3)) + pi4);
      v4f O6 = sp4(-2.f)*vfma4(C2f,nn, -n2);
      v4f O7 = sp4(-2.f)*(vfma4(C3f,q1, vfma4(-C2f,q2, sp4(C1f)*q3)) - pi4);

      fc1 = sp4(V1)*(E1+O1); fc2 = sp4(V2)*(E2+O2); fc3 = sp4(V3)*(E3+O3); fc4 = sp4(V4)*(E4+O4);
      fc5 = sp4(V5)*(E5+O5); fc6 = sp4(V6)*(E6+O6); fc7 = sp4(V7)*(E7+O7); fc8 = sp4(V8)*E8;
      fc9  = sp4(V7)*(E7-O7); fc10 = sp4(V6)*(E6-O6); fc11 = sp4(V5)*(E5-O5); fc12 = sp4(V4)*(E4-O4);
      fc13 = sp4(V3)*(E3-O3); fc14 = sp4(V2)*(E2-O2); fc15 = sp4(V1)*(E1-O1);
    }

    // ---- stage C: final OLA -> out[4ta .. 4ta+15] ----
    {
      float n1x = SH(fc1.x,+1), n1y = SH(fc1.y,+1);
      float n2x = SH(fc2.x,+1), n2y = SH(fc2.y,+1);
      float n3x = SH(fc3.x,+1), n3y = SH(fc3.y,+1);
      float n4 = SH(fc4.x,+1), n5 = SH(fc5.x,+1), n6 = SH(fc6.x,+1), n7 = SH(fc7.x,+1);
      float p12 = SH(fc12.w,-1), p13 = SH(fc13.w,-1), p14 = SH(fc14.w,-1), p15 = SH(fc15.w,-1);
      v4f g1 = mk4(fc1.z, fc1.w, n1x, n1y);
      v4f g2 = mk4(fc2.z, fc2.w, n2x, n2y);
      v4f g3 = mk4(fc3.z, fc3.w, n3x, n3y);
      v4f h4 = mk4(fc4.y, fc4.z, fc4.w, n4);
      v4f h5 = mk4(fc5.y, fc5.z, fc5.w, n5);
      v4f h6 = mk4(fc6.y, fc6.z, fc6.w, n6);
      v4f h7 = mk4(fc7.y, fc7.z, fc7.w, n7);
      v4f q12 = mk4(p12, fc12.x, fc12.y, fc12.z);
      v4f q13 = mk4(p13, fc13.x, fc13.y, fc13.z);
      v4f q14 = mk4(p14, fc14.x, fc14.y, fc14.z);
      v4f q15 = mk4(p15, fc15.x, fc15.y, fc15.z);
      v4f o0 = h4 + fc8  + q12;
      v4f o1 = g1 + h5 + fc9  + q13;
      v4f o2 = g2 + h6 + fc10 + q14;
      v4f o3 = g3 + h7 + fc11 + q15;
      if (lane >= 3 && lane <= 60 && ta < TMAX) {
        float* op = outb + 4*(size_t)ta;
        *(float4*)(op)      = make_float4(o0.x, o1.x, o2.x, o3.x);
        *(float4*)(op + 4)  = make_float4(o0.y, o1.y, o2.y, o3.y);
        *(float4*)(op + 8)  = make_float4(o0.z, o1.z, o2.z, o3.z);
        *(float4*)(op + 12) = make_float4(o0.w, o1.w, o2.w, o3.w);
      }
    }
    return;
  }

  // ---------------- edge blocks: validated LDS pipeline ----------------
  const int l0  = (bx == BXI) ? 0 : 261120;
  const int t4  = l0 >> 2;
  const int tAlo = t4 - 4;
  const int tBlo = t4 - 1;
  const int wbase = l0 - 12;

#pragma unroll
  for (int k = 0; k < KB; ++k) {
    const float* mrow = magb + (size_t)k * TFR + tAlo;
    for (int c = tid; c < NCA; c += 256) {
      int t = tAlo + c;
      s_mag[k * MSTR + c] = ((unsigned)t < (unsigned)TFR) ? mrow[c] : 0.f;
    }
  }
  __syncthreads();

  for (int f = tid; f < NCA; f += 256) {
    float R0 = s_mag[0*MSTR+f], R1 = s_mag[1*MSTR+f], R2 = s_mag[2*MSTR+f],
          R3 = s_mag[3*MSTR+f], R4 = s_mag[4*MSTR+f], R5 = s_mag[5*MSTR+f],
          R6 = s_mag[6*MSTR+f], R7 = s_mag[7*MSTR+f], R8 = s_mag[8*MSTR+f];
    float p1=R1+R7, m1=R1-R7, p2=R2+R6, m2=R2-R6, p3=R3+R5, m3=R3-R5;
    float tp=R0+R8, tm=R0-R8, d13=p1-p3;
    float E1 = fmaf(2.f, fmaf(C1f,m1, fmaf(C2f,m2, C3f*m3)), tm);
    float E2 = fmaf(2.f, fmaf(C2f,d13, -R4), tp);
    float E3 = fmaf(2.f, fmaf(C3f,m1, fmaf(-C2f,m2, -C1f*m3)), tm);
    float E4 = fmaf(2.f, R4-p2, tp);
    float E5 = fmaf(2.f, fmaf(-C3f,m1, fmaf(-C2f,m2, C1f*m3)), tm);
    float E6 = fmaf(-2.f, fmaf(C2f,d13, R4), tp);
    float E7 = fmaf(2.f, fmaf(-C1f,m1, fmaf(C2f,m2, -C3f*m3)), tm);
    float E8 = fmaf(2.f, ((p2+R4)-(p1+p3)), tp);
    float* rp = s_fab + f * FSTR;
    *(float4*)(rp+0)  = make_float4(0.f,   W1*E1, W2*E2, W3*E3);
    *(float4*)(rp+4)  = make_float4(W4*E4, W5*E5, W6*E6, W7*E7);
    *(float4*)(rp+8)  = make_float4(E8,    W7*E7, W6*E6, W5*E5);
    *(float4*)(rp+12) = make_float4(W4*E4, W3*E3, W2*E2, W1*E1);
  }
  __syncthreads();

  for (int i = tid; i < NW; i += 256) {
    int m = wbase + i;
    float val = 0.f;
    if (m >= 0 && m < LW) {
      int q = m + 8;
      int tq = q >> 2, r = q & 3;
      int base = (tq - tAlo) * FSTR + r;
      float acc = 0.f, env = 0.f;
#pragma unroll
      for (int j = 0; j < 4; ++j) {
        int t = tq - j;
        if ((unsigned)t < (unsigned)TFR) { acc += s_fab[base - 16*j]; env += W2C[r + 4*j]; }
      }
      val = acc * __builtin_amdgcn_rcpf(16.f * env);
    }
    s_wav[i] = val;
  }
  __syncthreads();

  for (int f = tid; f < NFB; f += 256) {
    float* rp = s_fab + f * FSTR;
    int t2 = tBlo + f;
    bool valid = ((unsigned)t2 < (unsigned)TFR);
    if (valid) {
      float xs[16];
      int g0 = 4*t2 - 8;
#pragma unroll
      for (int n = 0; n < 16; ++n) {
        int g = g0 + n;
        g = (g < 0) ? -g : g;
        g = (g < LW) ? g : (2*(LW-1) - g);
        xs[n] = s_wav[g - wbase];
      }
      float x1=xs[1]*W1, x2=xs[2]*W2, x3=xs[3]*W3, x4=xs[4]*W4, x5=xs[5]*W5,
            x6=xs[6]*W6, x7=xs[7]*W7, x8w=xs[8], x9=xs[9]*W7, x10=xs[10]*W6,
            x11=xs[11]*W5, x12=xs[12]*W4, x13=xs[13]*W3, x14=xs[14]*W2, x15=xs[15]*W1;
      float u1=x1+x15, v1=x1-x15, u2=x2+x14, v2=x2-x14, u3=x3+x13, v3=x3-x13,
            u4=x4+x12, v4=x4-x12, u5=x5+x11, v5=x5-x11, u6=x6+x10, v6=x6-x10,
            u7=x7+x9,  v7=x7-x9;
      float P1=u1+u7, M1=u1-u7, P2=u2+u6, M2=u2-u6, P3=u3+u5, M3=u3-u5;
      float D13 = P1-P3;
      float Sr0 = x8w + ((P1+P2)+(P3+u4));
      float Sr1 = fmaf(C1f,M1, fmaf(C2f,M2, C3f*M3)) - x8w;
      float Sr2 = fmaf(C2f,D13, x8w - u4);
      float Sr3 = fmaf(C3f,M1, fmaf(-C2f,M2, -C1f*M3)) - x8w;
      float Sr4 = (u4 - P2) + x8w;
      float Sr5 = fmaf(-C3f,M1, fmaf(-C2f,M2, C1f*M3)) - x8w;
      float Sr6 = fmaf(-C2f,D13, x8w - u4);
      float Sr7 = fmaf(-C1f,M1, fmaf(C2f,M2, -C3f*M3)) - x8w;
      float Sr8 = x8w + ((P2+u4)-(P1+P3));
      float Q1=v1+v7, N1=v1-v7, Q2=v2+v6, N2=v2-v6, Q3=v3+v5, N3=v3-v5;
      float NN = N1+N3;
      float Si1 = -(fmaf(C3f,Q1, fmaf(C2f,Q2, C1f*Q3)) + v4);
      float Si2 = -fmaf(C2f,NN, N2);
      float Si3 = -(fmaf(C1f,Q1, fmaf(C2f,Q2, -C3f*Q3)) - v4);
      float Si4 = N3 - N1;
      float Si5 = -(fmaf(C1f,Q1, fmaf(-C2f,Q2, -C3f*Q3)) + v4);
      float Si6 = fmaf(-C2f,NN, N2);
      float Si7 = -(fmaf(C3f,Q1, fmaf(-C2f,Q2, C1f*Q3)) - v4);

      const float* mcol = s_mag + (f + 3);
      float pr0,pr1,pr2,pr3,pr4,pr5,pr6,pr7,pr8;
      float pi1,pi2,pi3,pi4,pi5,pi6,pi7;
      { float mm = mcol[0];
        pr0 = (Sr0 >= 0.f) ? mm : -mm; }
      phase1(mcol[1*MSTR], Sr1, Si1, pr1, pi1);
      phase1(mcol[2*MSTR], Sr2, Si2, pr2, pi2);
      phase1(mcol[3*MSTR], Sr3, Si3, pr3, pi3);
      phase1(mcol[4*MSTR], Sr4, Si4, pr4, pi4);
      phase1(mcol[5*MSTR], Sr5, Si5, pr5, pi5);
      phase1(mcol[6*MSTR], Sr6, Si6, pr6, pi6);
      phase1(mcol[7*MSTR], Sr7, Si7, pr7, pi7);
      { float mm = mcol[8*MSTR];
        pr8 = (Sr8 >= 0.f) ? mm : -mm; }

      float ap1=pr1+pr7, bm1=pr1-pr7, ap2=pr2+pr6, bm2=pr2-pr6, ap3=pr3+pr5, bm3=pr3-pr5;
      float tp=pr0+pr8, tm=pr0-pr8, ed=ap1-ap3;
      float E1 = fmaf(2.f, fmaf(C1f,bm1, fmaf(C2f,bm2, C3f*bm3)), tm);
      float E2 = fmaf(2.f, fmaf(C2f,ed, -pr4), tp);
      float E3 = fmaf(2.f, fmaf(C3f,bm1, fmaf(-C2f,bm2, -C1f*bm3)), tm);
      float E4 = fmaf(2.f, pr4-ap2, tp);
      float E5 = fmaf(2.f, fmaf(-C3f,bm1, fmaf(-C2f,bm2, C1f*bm3)), tm);
      float E6 = fmaf(-2.f, fmaf(C2f,ed, pr4), tp);
      float E7 = fmaf(2.f, fmaf(-C1f,bm1, fmaf(C2f,bm2, -C3f*bm3)), tm);
      float E8 = fmaf(2.f, ((ap2+pr4)-(ap1+ap3)), tp);
      float q1=pi1+pi7, n1=pi1-pi7, q2=pi2+pi6, n2=pi2-pi6, q3=pi3+pi5, n3=pi3-pi5;
      float nn = n1+n3;
      float O1 = -2.f*(fmaf(C3f,q1, fmaf(C2f,q2, C1f*q3)) + pi4);
      float O2 = -2.f*fmaf(C2f,nn, n2);
      float O3 = -2.f*(fmaf(C1f,q1, fmaf(C2f,q2, -C3f*q3)) - pi4);
      float O4 = -2.f*(n1-n3);
      float O5 = -2.f*(fmaf(C1f,q1, fmaf(-C2f,q2, -C3f*q3)) + pi4);
      float O6 = -2.f*fmaf(C2f,nn, -n2);
      float O7 = -2.f*(fmaf(C3f,q1, fmaf(-C2f,q2, C1f*q3)) - pi4);

      *(float4*)(rp+0)  = make_float4(0.f,          W1*(E1+O1), W2*(E2+O2), W3*(E3+O3));
      *(float4*)(rp+4)  = make_float4(W4*(E4+O4),   W5*(E5+O5), W6*(E6+O6), W7*(E7+O7));
      *(float4*)(rp+8)  = make_float4(E8,           W7*(E7-O7), W6*(E6-O6), W5*(E5-O5));
      *(float4*)(rp+12) = make_float4(W4*(E4-O4),   W3*(E3-O3), W2*(E2-O2), W1*(E1-O1));
    } else {
      float4 z = make_float4(0.f,0.f,0.f,0.f);
      *(float4*)(rp+0)=z; *(float4*)(rp+4)=z; *(float4*)(rp+8)=z; *(float4*)(rp+12)=z;
    }
  }
  __syncthreads();

  for (int i = tid; i < TILE; i += 256) {
    int l = l0 + i;
    if (l < LW) {
      int q = l + 8;
      int tq = q >> 2, r = q & 3;
      int base = (tq - tBlo) * FSTR + r;
      float acc = 0.f, env = 0.f;
#pragma unroll
      for (int j = 0; j < 4; ++j) {
        int t = tq - j;
        if ((unsigned)t < (unsigned)TFR) { acc += s_fab[base - 16*j]; env += W2C[r + 4*j]; }
      }
      outb[l] = acc * __builtin_amdgcn_rcpf(16.f * env);
    }
  }
}

extern "C" void kernel_launch(void* const* d_in, const int* in_sizes, int n_in,
                              void* d_out, int out_size, void* d_ws, size_t ws_size,
                              hipStream_t stream) {
  const float* mag = (const float*)d_in[0];   // (32, 9, 65536) f32
  float* out = (float*)d_out;                 // (32, 262140) f32
  dim3 grid(BXI + 2, 32);                     // 71 interior + 2 edge blocks/batch
  istft_all<<<grid, 256, 0, stream>>>(mag, out);
}